// Round 7
// baseline (207.046 us; speedup 1.0000x reference)
//
#include <hip/hip_runtime.h>
#include <stdint.h>

#define D 128
#define SIGMA 0.1f

typedef unsigned int uint;
typedef unsigned short ushort;

typedef short s8v __attribute__((ext_vector_type(8)));   // 8 bf16 as shorts (4 VGPR)
typedef float f32x4 __attribute__((ext_vector_type(4)));

union U4S8 { uint4 u; s8v s; };

// ---------------- Threefry-2x32 (20 rounds), matches JAX/XLA ----------------
__host__ __device__ inline void tf2x32(uint32_t k0, uint32_t k1,
                                       uint32_t x0, uint32_t x1,
                                       uint32_t& o0, uint32_t& o1) {
  const uint32_t ks2 = k0 ^ k1 ^ 0x1BD11BDAu;
#define ROTL(v, r) (((v) << (r)) | ((v) >> (32 - (r))))
#define RND(R) { x0 += x1; x1 = ROTL(x1, R); x1 ^= x0; }
  x0 += k0; x1 += k1;
  RND(13) RND(15) RND(26) RND(6)
  x0 += k1; x1 += ks2 + 1u;
  RND(17) RND(29) RND(16) RND(24)
  x0 += ks2; x1 += k0 + 2u;
  RND(13) RND(15) RND(26) RND(6)
  x0 += k0; x1 += k1 + 3u;
  RND(17) RND(29) RND(16) RND(24)
  x0 += k1; x1 += ks2 + 4u;
  RND(13) RND(15) RND(26) RND(6)
  x0 += ks2; x1 += k0 + 5u;
#undef RND
#undef ROTL
  o0 = x0; o1 = x1;
}

// JAX partitionable random_bits (32-bit): bits[j] = o0 ^ o1 of block(key,(0,j)),
// then uniform in [-1+ulp, 1), then sqrt(2)*erfinv (XLA Giles f32 polynomial).
__device__ inline float jax_normal(uint32_t k0, uint32_t k1, uint32_t idx) {
  uint32_t o0, o1;
  tf2x32(k0, k1, 0u, idx, o0, o1);
  uint32_t bits = o0 ^ o1;
  float f = __uint_as_float((bits >> 9) | 0x3f800000u) - 1.0f;
  const float lo = __uint_as_float(0xBF7FFFFFu); // nextafter(-1,0)
  float u = fmaxf(lo, f * 2.0f + lo);
  float w = -__logf((1.0f - u) * (1.0f + u));    // = -log1p(-u*u)
  float p;
  if (w < 5.0f) {
    w -= 2.5f;
    p = 2.81022636e-08f;
    p = fmaf(p, w, 3.43273939e-07f);
    p = fmaf(p, w, -3.5233877e-06f);
    p = fmaf(p, w, -4.39150654e-06f);
    p = fmaf(p, w, 0.00021858087f);
    p = fmaf(p, w, -0.00125372503f);
    p = fmaf(p, w, -0.00417768164f);
    p = fmaf(p, w, 0.246640727f);
    p = fmaf(p, w, 1.50140941f);
  } else {
    w = sqrtf(w) - 3.0f;
    p = -0.000200214257f;
    p = fmaf(p, w, 0.000100950558f);
    p = fmaf(p, w, 0.00134934322f);
    p = fmaf(p, w, -0.00367342844f);
    p = fmaf(p, w, 0.00573950773f);
    p = fmaf(p, w, -0.0076224613f);
    p = fmaf(p, w, 0.00943887047f);
    p = fmaf(p, w, 1.00167406f);
    p = fmaf(p, w, 2.83297682f);
  }
  return 1.41421356237f * (p * u);
}

__device__ inline uint bf16r(float f) {  // round-to-nearest-even bf16 bits
  uint u = __float_as_uint(f);
  return (u + 0x7fffu + ((u >> 16) & 1u)) >> 16;
}

// unpack 8 bf16 (uint4) -> 8 floats
__device__ inline void unpk8(uint4 u, float* a) {
  a[0] = __uint_as_float(u.x << 16);
  a[1] = __uint_as_float(u.x & 0xffff0000u);
  a[2] = __uint_as_float(u.y << 16);
  a[3] = __uint_as_float(u.y & 0xffff0000u);
  a[4] = __uint_as_float(u.z << 16);
  a[5] = __uint_as_float(u.z & 0xffff0000u);
  a[6] = __uint_as_float(u.w << 16);
  a[7] = __uint_as_float(u.w & 0xffff0000u);
}

template<int USEB>
__device__ inline void ldrow16(const float* __restrict__ hf,
                               const uint4* __restrict__ hb,
                               int node, int sl, float* a) {
  if (USEB) {
    unpk8(hb[node * 16 + sl], a);
  } else {
    float4 v0 = ((const float4*)hf)[node * 32 + sl * 2];
    float4 v1 = ((const float4*)hf)[node * 32 + sl * 2 + 1];
    a[0] = v0.x; a[1] = v0.y; a[2] = v0.z; a[3] = v0.w;
    a[4] = v1.x; a[5] = v1.y; a[6] = v1.z; a[7] = v1.w;
  }
}

// ---------------- workspace zeroing (rocclr fillBuffer has huge latency) ----
__global__ __launch_bounds__(256) void k_zero(int4* __restrict__ p, int n4) {
  int i = blockIdx.x * blockDim.x + threadIdx.x;
  if (i < n4) p[i] = make_int4(0, 0, 0, 0);
}

// ---------------- CSR build ----------------
__global__ __launch_bounds__(256) void k_hist(const int* __restrict__ dst,
                                              int* __restrict__ cnt, int E) {
  int i = (blockIdx.x * blockDim.x + threadIdx.x) * 4;
  if (i + 3 < E) {
    int4 d = *(const int4*)(dst + i);
    atomicAdd(&cnt[d.x], 1);
    atomicAdd(&cnt[d.y], 1);
    atomicAdd(&cnt[d.z], 1);
    atomicAdd(&cnt[d.w], 1);
  } else {
    for (int j = i; j < E; ++j) atomicAdd(&cnt[dst[j]], 1);
  }
}

__global__ __launch_bounds__(256) void k_bsum(const int* __restrict__ cnt,
                                              int* __restrict__ bsum, int N) {
  __shared__ int ws[4];
  int b = blockIdx.x, t = threadIdx.x;
  int base = b * 1024 + t * 4;
  int4 c = {0, 0, 0, 0};
  if (base + 3 < N) c = *(const int4*)(cnt + base);
  else {
    if (base < N) c.x = cnt[base];
    if (base + 1 < N) c.y = cnt[base + 1];
    if (base + 2 < N) c.z = cnt[base + 2];
    if (base + 3 < N) c.w = cnt[base + 3];
  }
  int s = c.x + c.y + c.z + c.w;
  #pragma unroll
  for (int off = 32; off; off >>= 1) s += __shfl_xor(s, off);
  if ((t & 63) == 0) ws[t >> 6] = s;
  __syncthreads();
  if (t == 0) bsum[b] = ws[0] + ws[1] + ws[2] + ws[3];
}

// apply with fused block-sum scan (NB <= 64): no separate k_bscan dispatch
__global__ __launch_bounds__(256) void k_apply2(const int* __restrict__ cnt,
                                                const int* __restrict__ bsum,
                                                int* __restrict__ row,
                                                int* __restrict__ cur,
                                                int N, int NB) {
  __shared__ int sboff;
  __shared__ int wsum[4];
  int b = blockIdx.x, t = threadIdx.x;
  if (t < 64) {
    int v = (t < NB) ? bsum[t] : 0;
    int incl = v;
    #pragma unroll
    for (int off = 1; off < 64; off <<= 1) {
      int tv = __shfl_up(incl, off);
      if (t >= off) incl += tv;
    }
    if (t == b) sboff = incl - v;                 // exclusive prefix at b
    if (b == 0 && t == NB - 1) row[N] = incl;     // grand total, written once
  }
  __syncthreads();

  int base = b * 1024 + t * 4;
  int4 c = {0, 0, 0, 0};
  if (base + 3 < N) c = *(const int4*)(cnt + base);
  else {
    if (base < N) c.x = cnt[base];
    if (base + 1 < N) c.y = cnt[base + 1];
    if (base + 2 < N) c.z = cnt[base + 2];
    if (base + 3 < N) c.w = cnt[base + 3];
  }
  int s = c.x + c.y + c.z + c.w;
  int incl = s;
  #pragma unroll
  for (int off = 1; off < 64; off <<= 1) {
    int tv = __shfl_up(incl, off);
    if ((t & 63) >= off) incl += tv;
  }
  int wid = t >> 6;
  if ((t & 63) == 63) wsum[wid] = incl;
  __syncthreads();
  int woff = 0;
  for (int w = 0; w < wid; ++w) woff += wsum[w];
  int ex = sboff + woff + incl - s;
  int r0 = ex, r1 = ex + c.x, r2 = r1 + c.y, r3 = r2 + c.z;
  if (base + 3 < N) {
    *(int4*)(row + base) = make_int4(r0, r1, r2, r3);
    *(int4*)(cur + base) = make_int4(r0, r1, r2, r3);
  } else {
    if (base < N)     { row[base] = r0;     cur[base] = r0; }
    if (base + 1 < N) { row[base + 1] = r1; cur[base + 1] = r1; }
    if (base + 2 < N) { row[base + 2] = r2; cur[base + 2] = r2; }
  }
}

// generic fallback scan kernels (NB > 64)
__global__ void k_bscan(const int* __restrict__ bsum, int* __restrict__ boff,
                        int* __restrict__ rowN, int NB) {
  int lane = threadIdx.x;
  int carry = 0;
  for (int base = 0; base < NB; base += 64) {
    int idx = base + lane;
    int v = (idx < NB) ? bsum[idx] : 0;
    int incl = v;
    #pragma unroll
    for (int off = 1; off < 64; off <<= 1) {
      int t = __shfl_up(incl, off);
      if (lane >= off) incl += t;
    }
    if (idx < NB) boff[idx] = carry + incl - v;
    carry += __shfl(incl, 63);
  }
  if (lane == 0) rowN[0] = carry;
}

__global__ __launch_bounds__(256) void k_apply(const int* __restrict__ cnt,
                                               const int* __restrict__ boff,
                                               int* __restrict__ row,
                                               int* __restrict__ cur, int N) {
  __shared__ int wsum[4];
  int b = blockIdx.x, t = threadIdx.x;
  int base = b * 1024 + t * 4;
  int4 c = {0, 0, 0, 0};
  if (base + 3 < N) c = *(const int4*)(cnt + base);
  else {
    if (base < N) c.x = cnt[base];
    if (base + 1 < N) c.y = cnt[base + 1];
    if (base + 2 < N) c.z = cnt[base + 2];
    if (base + 3 < N) c.w = cnt[base + 3];
  }
  int s = c.x + c.y + c.z + c.w;
  int incl = s;
  #pragma unroll
  for (int off = 1; off < 64; off <<= 1) {
    int tv = __shfl_up(incl, off);
    if ((t & 63) >= off) incl += tv;
  }
  int wid = t >> 6;
  if ((t & 63) == 63) wsum[wid] = incl;
  __syncthreads();
  int woff = 0;
  for (int w = 0; w < wid; ++w) woff += wsum[w];
  int ex = boff[b] + woff + incl - s;
  int r0 = ex, r1 = ex + c.x, r2 = r1 + c.y, r3 = r2 + c.z;
  if (base + 3 < N) {
    *(int4*)(row + base) = make_int4(r0, r1, r2, r3);
    *(int4*)(cur + base) = make_int4(r0, r1, r2, r3);
  } else {
    if (base < N)     { row[base] = r0;     cur[base] = r0; }
    if (base + 1 < N) { row[base + 1] = r1; cur[base + 1] = r1; }
    if (base + 2 < N) { row[base + 2] = r2; cur[base + 2] = r2; }
  }
}

__global__ __launch_bounds__(256) void k_fill(const int* __restrict__ src,
                                              const int* __restrict__ dst,
                                              int* __restrict__ cur,
                                              int* __restrict__ csr, int E) {
  int i = (blockIdx.x * blockDim.x + threadIdx.x) * 4;
  if (i + 3 < E) {
    int4 d = *(const int4*)(dst + i);
    int4 s = *(const int4*)(src + i);
    csr[atomicAdd(&cur[d.x], 1)] = s.x;
    csr[atomicAdd(&cur[d.y], 1)] = s.y;
    csr[atomicAdd(&cur[d.z], 1)] = s.z;
    csr[atomicAdd(&cur[d.w], 1)] = s.w;
  } else {
    for (int j = i; j < E; ++j) csr[atomicAdd(&cur[dst[j]], 1)] = src[j];
  }
}

// ---------------- h0 = l2_normalize(x), optional bf16 mirror ----------------
template<int USEB>
__global__ __launch_bounds__(256) void k_norm0(const float* __restrict__ x,
                                               float* __restrict__ h,
                                               uint2* __restrict__ hb, int N) {
  int gid = blockIdx.x * blockDim.x + threadIdx.x;
  int node = gid >> 5, lane = gid & 31;
  if (node >= N) return;
  float4 v = ((const float4*)x)[node * 32 + lane];
  float ss = v.x * v.x + v.y * v.y + v.z * v.z + v.w * v.w;
  #pragma unroll
  for (int off = 16; off; off >>= 1) ss += __shfl_xor(ss, off);
  float inv = 1.0f / fmaxf(sqrtf(ss), 1e-12f);
  float4 o; o.x = v.x * inv; o.y = v.y * inv; o.z = v.z * inv; o.w = v.w * inv;
  ((float4*)h)[node * 32 + lane] = o;
  if (USEB) {
    uint2 u;
    u.x = bf16r(o.x) | (bf16r(o.y) << 16);
    u.y = bf16r(o.z) | (bf16r(o.w) << 16);
    hb[node * 32 + lane] = u;
  }
}

// ---------------- one hop (MFMA dots): fused alpha+aggregate+noise+normalize -
// One wave per node, 16 edges per block iteration.
// Dots: mfma_f32_16x16x32_bf16 with A = 16 gathered edge rows (lane l supplies
// edge l&15, k-chunk q*4+(l>>4)), B = h[node] replicated over 16 cols (lane l
// supplies hv[k=(l>>4)*8+i]). D: lane l holds dots of edges (l>>4)*4+j — which
// is exactly what group g=(l>>4) consumes in the row-layout accumulation.
__global__ __launch_bounds__(256) void k_hop_mfma(
    const uint4* __restrict__ hpb,
    float* __restrict__ hof, uint* __restrict__ hob, int wb,
    const int* __restrict__ row, const int* __restrict__ csr,
    int N, uint32_t k0, uint32_t k1) {
  int gid = blockIdx.x * blockDim.x + threadIdx.x;
  int node = gid >> 6;
  if (node >= N) return;
  int lane = threadIdx.x & 63;
  int sl = lane & 15, g = lane >> 4;

  int b = row[node], e = row[node + 1];

  // B fragment: node's own row, chunk q*4+g per mfma q (packed bf16)
  U4S8 bf0, bf1, bf2, bf3;
  bf0.u = hpb[node * 16 + 0 * 4 + g];
  bf1.u = hpb[node * 16 + 1 * 4 + g];
  bf2.u = hpb[node * 16 + 2 * 4 + g];
  bf3.u = hpb[node * 16 + 3 * 4 + g];

  float acc[8] = {0.f, 0.f, 0.f, 0.f, 0.f, 0.f, 0.f, 0.f};

  for (int cb = b; cb < e; cb += 16) {
    // lane's A-row edge = sl (lanes 16-63 replicate lanes 0-15's csr reads)
    int sA = csr[min(cb + sl, e - 1)];
    U4S8 af0, af1, af2, af3;
    af0.u = hpb[sA * 16 + 0 * 4 + g];
    af1.u = hpb[sA * 16 + 1 * 4 + g];
    af2.u = hpb[sA * 16 + 2 * 4 + g];
    af3.u = hpb[sA * 16 + 3 * 4 + g];

    // row-layout gather for accumulation: group g's 4 edges, lane holds chunk sl
    int i0 = __shfl(sA, g * 4 + 0);
    int i1 = __shfl(sA, g * 4 + 1);
    int i2 = __shfl(sA, g * 4 + 2);
    int i3 = __shfl(sA, g * 4 + 3);
    uint4 u0 = hpb[i0 * 16 + sl];
    uint4 u1 = hpb[i1 * 16 + sl];
    uint4 u2 = hpb[i2 * 16 + sl];
    uint4 u3 = hpb[i3 * 16 + sl];

    f32x4 dfr = {0.f, 0.f, 0.f, 0.f};
    dfr = __builtin_amdgcn_mfma_f32_16x16x32_bf16(af0.s, bf0.s, dfr, 0, 0, 0);
    dfr = __builtin_amdgcn_mfma_f32_16x16x32_bf16(af1.s, bf1.s, dfr, 0, 0, 0);
    dfr = __builtin_amdgcn_mfma_f32_16x16x32_bf16(af2.s, bf2.s, dfr, 0, 0, 0);
    dfr = __builtin_amdgcn_mfma_f32_16x16x32_bf16(af3.s, bf3.s, dfr, 0, 0, 0);
    // dfr[j] = dot of edge cb + g*4 + j  (identical across sl)

    float al0 = (cb + g * 4 + 0 < e) ? __builtin_amdgcn_rcpf(1.0f + __expf(-dfr[0])) : 0.f;
    float al1 = (cb + g * 4 + 1 < e) ? __builtin_amdgcn_rcpf(1.0f + __expf(-dfr[1])) : 0.f;
    float al2 = (cb + g * 4 + 2 < e) ? __builtin_amdgcn_rcpf(1.0f + __expf(-dfr[2])) : 0.f;
    float al3 = (cb + g * 4 + 3 < e) ? __builtin_amdgcn_rcpf(1.0f + __expf(-dfr[3])) : 0.f;

    float a0[8], a1[8], a2[8], a3[8];
    unpk8(u0, a0); unpk8(u1, a1); unpk8(u2, a2); unpk8(u3, a3);
    #pragma unroll
    for (int t = 0; t < 8; ++t) {
      acc[t] = fmaf(al0, a0[t], acc[t]);
      acc[t] = fmaf(al1, a1[t], acc[t]);
      acc[t] = fmaf(al2, a2[t], acc[t]);
      acc[t] = fmaf(al3, a3[t], acc[t]);
    }
  }

  // combine the 4 groups: acc[t] becomes total, replicated across groups
  #pragma unroll
  for (int t = 0; t < 8; ++t) {
    acc[t] += __shfl_xor(acc[t], 16);
    acc[t] += __shfl_xor(acc[t], 32);
  }

  // lane (sl,g) owns elems sl*8 + 2g, sl*8 + 2g + 1 (static reg selection)
  float p0s = (g & 1) ? acc[2] : acc[0];
  float p1s = (g & 1) ? acc[3] : acc[1];
  float q0s = (g & 1) ? acc[6] : acc[4];
  float q1s = (g & 1) ? acc[7] : acc[5];
  float s0 = (g & 2) ? q0s : p0s;
  float s1 = (g & 2) ? q1s : p1s;

  uint32_t j0 = (uint32_t)node * 128u + (uint32_t)sl * 8u + (uint32_t)g * 2u;
  s0 += SIGMA * jax_normal(k0, k1, j0);
  s1 += SIGMA * jax_normal(k0, k1, j0 + 1u);

  float ss = s0 * s0 + s1 * s1;
  #pragma unroll
  for (int off = 32; off; off >>= 1) ss += __shfl_xor(ss, off);
  float inv = __builtin_amdgcn_rcpf(fmaxf(sqrtf(ss), 1e-12f));
  float o0 = s0 * inv, o1 = s1 * inv;
  int oi = node * 64 + sl * 4 + g;       // float2 slot = elem pair position
  ((float2*)hof)[oi] = make_float2(o0, o1);
  if (wb) hob[oi] = bf16r(o0) | (bf16r(o1) << 16);
}

// f32 fallback hop (only if workspace too small for bf16 mirrors)
__global__ __launch_bounds__(256) void k_hop_f32(
    const float* __restrict__ hpf, float* __restrict__ hof,
    const int* __restrict__ row, const int* __restrict__ csr,
    int N, uint32_t k0, uint32_t k1) {
  int gid = blockIdx.x * blockDim.x + threadIdx.x;
  int node = gid >> 6;
  if (node >= N) return;
  int lane = threadIdx.x & 63;
  int sl = lane & 15, g = lane >> 4;

  float hv[8];
  ldrow16<0>(hpf, nullptr, node, sl, hv);
  float acc[8] = {0.f, 0.f, 0.f, 0.f, 0.f, 0.f, 0.f, 0.f};
  int b = row[node], e = row[node + 1];
  for (int cb = b; cb < e; cb += 64) {
    int cn = min(64, e - cb);
    int eidx = csr[min(cb + lane, e - 1)];
    for (int jb = 0; jb < cn; jb += 16) {
      int pos = jb + (g << 2);
      int i0 = __shfl(eidx, pos);
      int i1 = __shfl(eidx, pos + 1);
      int i2 = __shfl(eidx, pos + 2);
      int i3 = __shfl(eidx, pos + 3);
      float a0[8], a1[8], a2[8], a3[8];
      ldrow16<0>(hpf, nullptr, i0, sl, a0);
      ldrow16<0>(hpf, nullptr, i1, sl, a1);
      ldrow16<0>(hpf, nullptr, i2, sl, a2);
      ldrow16<0>(hpf, nullptr, i3, sl, a3);
      float p0 = 0.f, p1 = 0.f, p2 = 0.f, p3 = 0.f;
      #pragma unroll
      for (int t = 0; t < 8; ++t) {
        p0 = fmaf(a0[t], hv[t], p0);
        p1 = fmaf(a1[t], hv[t], p1);
        p2 = fmaf(a2[t], hv[t], p2);
        p3 = fmaf(a3[t], hv[t], p3);
      }
      #pragma unroll
      for (int off = 1; off < 16; off <<= 1) {
        p0 += __shfl_xor(p0, off);
        p1 += __shfl_xor(p1, off);
        p2 += __shfl_xor(p2, off);
        p3 += __shfl_xor(p3, off);
      }
      float al0 = (pos     < cn) ? __builtin_amdgcn_rcpf(1.0f + __expf(-p0)) : 0.f;
      float al1 = (pos + 1 < cn) ? __builtin_amdgcn_rcpf(1.0f + __expf(-p1)) : 0.f;
      float al2 = (pos + 2 < cn) ? __builtin_amdgcn_rcpf(1.0f + __expf(-p2)) : 0.f;
      float al3 = (pos + 3 < cn) ? __builtin_amdgcn_rcpf(1.0f + __expf(-p3)) : 0.f;
      #pragma unroll
      for (int t = 0; t < 8; ++t) {
        acc[t] = fmaf(al0, a0[t], acc[t]);
        acc[t] = fmaf(al1, a1[t], acc[t]);
        acc[t] = fmaf(al2, a2[t], acc[t]);
        acc[t] = fmaf(al3, a3[t], acc[t]);
      }
    }
  }
  #pragma unroll
  for (int t = 0; t < 8; ++t) {
    acc[t] += __shfl_xor(acc[t], 16);
    acc[t] += __shfl_xor(acc[t], 32);
  }
  float p0s = (g & 1) ? acc[2] : acc[0];
  float p1s = (g & 1) ? acc[3] : acc[1];
  float q0s = (g & 1) ? acc[6] : acc[4];
  float q1s = (g & 1) ? acc[7] : acc[5];
  float s0 = (g & 2) ? q0s : p0s;
  float s1 = (g & 2) ? q1s : p1s;

  uint32_t j0 = (uint32_t)node * 128u + (uint32_t)sl * 8u + (uint32_t)g * 2u;
  s0 += SIGMA * jax_normal(k0, k1, j0);
  s1 += SIGMA * jax_normal(k0, k1, j0 + 1u);

  float ss = s0 * s0 + s1 * s1;
  #pragma unroll
  for (int off = 32; off; off >>= 1) ss += __shfl_xor(ss, off);
  float inv = __builtin_amdgcn_rcpf(fmaxf(sqrtf(ss), 1e-12f));
  float o0 = s0 * inv, o1 = s1 * inv;
  int oi = node * 64 + sl * 4 + g;
  ((float2*)hof)[oi] = make_float2(o0, o1);
}

extern "C" void kernel_launch(void* const* d_in, const int* in_sizes, int n_in,
                              void* d_out, int out_size, void* d_ws, size_t ws_size,
                              hipStream_t stream) {
  const float* x = (const float*)d_in[0];
  const int* ei = (const int*)d_in[1];
  int N = in_sizes[0] / D;
  int E = in_sizes[1] / 2;
  const int* src = ei;
  const int* dst = ei + E;
  float* out = (float*)d_out;
  size_t nd = (size_t)N * D;

  int Np = (N + 3) & ~3;
  int Ep = (E + 3) & ~3;
  int NB = (N + 1023) / 1024;
  int NBp = (NB + 3) & ~3;
  int* cnt  = (int*)d_ws;             // Np
  int* row  = cnt + Np;               // Np + 4
  int* cur  = row + Np + 4;           // Np
  int* csr  = cur + Np;               // Ep
  int* bsum = csr + Ep;               // NBp
  int* boff = bsum + NBp;             // NBp

  size_t int_bytes = ((size_t)(3 * Np + 4 + Ep + 2 * NBp)) * 4;
  size_t hb_off = (int_bytes + 255) & ~(size_t)255;
  size_t hb_bytes = (size_t)N * D * 2;      // one bf16 h buffer
  bool useb = ws_size >= hb_off + 2 * hb_bytes;
  ushort* hb0 = (ushort*)((char*)d_ws + hb_off);
  ushort* hb1 = hb0 + (size_t)N * D;

  int n4 = Np / 4;
  k_zero<<<(n4 + 255) / 256, 256, 0, stream>>>((int4*)cnt, n4);
  int eb4 = (E / 4 + 256) / 256;
  k_hist<<<eb4, 256, 0, stream>>>(dst, cnt, E);
  k_bsum<<<NB, 256, 0, stream>>>(cnt, bsum, N);
  if (NB <= 64) {
    k_apply2<<<NB, 256, 0, stream>>>(cnt, bsum, row, cur, N, NB);
  } else {
    k_bscan<<<1, 64, 0, stream>>>(bsum, boff, row + N, NB);
    k_apply<<<NB, 256, 0, stream>>>(cnt, boff, row, cur, N);
  }
  k_fill<<<eb4, 256, 0, stream>>>(src, dst, cur, csr, E);

  int nb32 = (N * 32 + 255) / 256;
  int nb64 = (N * 64 + 255) / 256;

  if (useb) {
    k_norm0<1><<<nb32, 256, 0, stream>>>(x, out, (uint2*)hb0, N);
    for (int k = 0; k < 3; ++k) {
      uint32_t ka, kb;
      tf2x32(0u, 42u, 0u, (uint32_t)k, ka, kb);
      const uint4* hin = (const uint4*)((k & 1) ? hb1 : hb0);
      uint* hout = (uint*)((k & 1) ? hb0 : hb1);
      k_hop_mfma<<<nb64, 256, 0, stream>>>(hin,
                                           out + (size_t)(k + 1) * nd, hout,
                                           (k < 2) ? 1 : 0,
                                           row, csr, N, ka, kb);
    }
  } else {
    k_norm0<0><<<nb32, 256, 0, stream>>>(x, out, nullptr, N);
    for (int k = 0; k < 3; ++k) {
      uint32_t ka, kb;
      tf2x32(0u, 42u, 0u, (uint32_t)k, ka, kb);
      k_hop_f32<<<nb64, 256, 0, stream>>>(out + (size_t)k * nd,
                                          out + (size_t)(k + 1) * nd,
                                          row, csr, N, ka, kb);
    }
  }
}

// Round 8
// 181.575 us; speedup vs baseline: 1.1403x; 1.1403x over previous
//
#include <hip/hip_runtime.h>
#include <stdint.h>

#define D 128
#define SIGMA 0.1f

typedef unsigned int uint;
typedef unsigned short ushort;

#if __has_builtin(__builtin_amdgcn_fdot2_f32_bf16)
#define HAVE_DOT2 1
typedef __bf16 bf16x2 __attribute__((ext_vector_type(2)));
__device__ inline float dot2b(uint a, uint b, float c) {
  union { uint u; bf16x2 v; } ua, ub;
  ua.u = a; ub.u = b;
  return __builtin_amdgcn_fdot2_f32_bf16(ua.v, ub.v, c, false);
}
#else
#define HAVE_DOT2 0
#endif

typedef float v2f __attribute__((ext_vector_type(2)));

// ---------------- Threefry-2x32 (20 rounds), matches JAX/XLA ----------------
__host__ __device__ inline void tf2x32(uint32_t k0, uint32_t k1,
                                       uint32_t x0, uint32_t x1,
                                       uint32_t& o0, uint32_t& o1) {
  const uint32_t ks2 = k0 ^ k1 ^ 0x1BD11BDAu;
#define ROTL(v, r) (((v) << (r)) | ((v) >> (32 - (r))))
#define RND(R) { x0 += x1; x1 = ROTL(x1, R); x1 ^= x0; }
  x0 += k0; x1 += k1;
  RND(13) RND(15) RND(26) RND(6)
  x0 += k1; x1 += ks2 + 1u;
  RND(17) RND(29) RND(16) RND(24)
  x0 += ks2; x1 += k0 + 2u;
  RND(13) RND(15) RND(26) RND(6)
  x0 += k0; x1 += k1 + 3u;
  RND(17) RND(29) RND(16) RND(24)
  x0 += k1; x1 += ks2 + 4u;
  RND(13) RND(15) RND(26) RND(6)
  x0 += ks2; x1 += k0 + 5u;
#undef RND
#undef ROTL
  o0 = x0; o1 = x1;
}

// JAX partitionable random_bits (32-bit): bits[j] = o0 ^ o1 of block(key,(0,j)),
// then uniform in [-1+ulp, 1), then sqrt(2)*erfinv (XLA Giles f32 polynomial).
__device__ inline float jax_normal(uint32_t k0, uint32_t k1, uint32_t idx) {
  uint32_t o0, o1;
  tf2x32(k0, k1, 0u, idx, o0, o1);
  uint32_t bits = o0 ^ o1;
  float f = __uint_as_float((bits >> 9) | 0x3f800000u) - 1.0f;
  const float lo = __uint_as_float(0xBF7FFFFFu); // nextafter(-1,0)
  float u = fmaxf(lo, f * 2.0f + lo);
  float w = -__logf((1.0f - u) * (1.0f + u));    // = -log1p(-u*u)
  float p;
  if (w < 5.0f) {
    w -= 2.5f;
    p = 2.81022636e-08f;
    p = fmaf(p, w, 3.43273939e-07f);
    p = fmaf(p, w, -3.5233877e-06f);
    p = fmaf(p, w, -4.39150654e-06f);
    p = fmaf(p, w, 0.00021858087f);
    p = fmaf(p, w, -0.00125372503f);
    p = fmaf(p, w, -0.00417768164f);
    p = fmaf(p, w, 0.246640727f);
    p = fmaf(p, w, 1.50140941f);
  } else {
    w = sqrtf(w) - 3.0f;
    p = -0.000200214257f;
    p = fmaf(p, w, 0.000100950558f);
    p = fmaf(p, w, 0.00134934322f);
    p = fmaf(p, w, -0.00367342844f);
    p = fmaf(p, w, 0.00573950773f);
    p = fmaf(p, w, -0.0076224613f);
    p = fmaf(p, w, 0.00943887047f);
    p = fmaf(p, w, 1.00167406f);
    p = fmaf(p, w, 2.83297682f);
  }
  return 1.41421356237f * (p * u);
}

__device__ inline uint bf16r(float f) {  // round-to-nearest-even bf16 bits
  uint u = __float_as_uint(f);
  return (u + 0x7fffu + ((u >> 16) & 1u)) >> 16;
}

// unpack 8 bf16 (uint4) -> 8 floats
__device__ inline void unpk8(uint4 u, float* a) {
  a[0] = __uint_as_float(u.x << 16);
  a[1] = __uint_as_float(u.x & 0xffff0000u);
  a[2] = __uint_as_float(u.y << 16);
  a[3] = __uint_as_float(u.y & 0xffff0000u);
  a[4] = __uint_as_float(u.z << 16);
  a[5] = __uint_as_float(u.z & 0xffff0000u);
  a[6] = __uint_as_float(u.w << 16);
  a[7] = __uint_as_float(u.w & 0xffff0000u);
}

// unpack 8 bf16 (uint4) -> 4x v2f
__device__ inline void unpk8v(uint4 u, v2f* a) {
  a[0] = v2f{__uint_as_float(u.x << 16), __uint_as_float(u.x & 0xffff0000u)};
  a[1] = v2f{__uint_as_float(u.y << 16), __uint_as_float(u.y & 0xffff0000u)};
  a[2] = v2f{__uint_as_float(u.z << 16), __uint_as_float(u.z & 0xffff0000u)};
  a[3] = v2f{__uint_as_float(u.w << 16), __uint_as_float(u.w & 0xffff0000u)};
}

template<int USEB>
__device__ inline void ldrow16(const float* __restrict__ hf,
                               const uint4* __restrict__ hb,
                               int node, int sl, float* a) {
  if (USEB) {
    unpk8(hb[node * 16 + sl], a);
  } else {
    float4 v0 = ((const float4*)hf)[node * 32 + sl * 2];
    float4 v1 = ((const float4*)hf)[node * 32 + sl * 2 + 1];
    a[0] = v0.x; a[1] = v0.y; a[2] = v0.z; a[3] = v0.w;
    a[4] = v1.x; a[5] = v1.y; a[6] = v1.z; a[7] = v1.w;
  }
}

// ---------------- workspace zeroing (rocclr fillBuffer has huge latency) ----
__global__ __launch_bounds__(256) void k_zero(int4* __restrict__ p, int n4) {
  int i = blockIdx.x * blockDim.x + threadIdx.x;
  if (i < n4) p[i] = make_int4(0, 0, 0, 0);
}

// ---------------- CSR build ----------------
__global__ __launch_bounds__(256) void k_hist(const int* __restrict__ dst,
                                              int* __restrict__ cnt, int E) {
  int i = (blockIdx.x * blockDim.x + threadIdx.x) * 4;
  if (i + 3 < E) {
    int4 d = *(const int4*)(dst + i);
    atomicAdd(&cnt[d.x], 1);
    atomicAdd(&cnt[d.y], 1);
    atomicAdd(&cnt[d.z], 1);
    atomicAdd(&cnt[d.w], 1);
  } else {
    for (int j = i; j < E; ++j) atomicAdd(&cnt[dst[j]], 1);
  }
}

__global__ __launch_bounds__(256) void k_bsum(const int* __restrict__ cnt,
                                              int* __restrict__ bsum, int N) {
  __shared__ int ws[4];
  int b = blockIdx.x, t = threadIdx.x;
  int base = b * 1024 + t * 4;
  int4 c = {0, 0, 0, 0};
  if (base + 3 < N) c = *(const int4*)(cnt + base);
  else {
    if (base < N) c.x = cnt[base];
    if (base + 1 < N) c.y = cnt[base + 1];
    if (base + 2 < N) c.z = cnt[base + 2];
    if (base + 3 < N) c.w = cnt[base + 3];
  }
  int s = c.x + c.y + c.z + c.w;
  #pragma unroll
  for (int off = 32; off; off >>= 1) s += __shfl_xor(s, off);
  if ((t & 63) == 0) ws[t >> 6] = s;
  __syncthreads();
  if (t == 0) bsum[b] = ws[0] + ws[1] + ws[2] + ws[3];
}

// apply with fused block-sum scan (NB <= 64): no separate k_bscan dispatch
__global__ __launch_bounds__(256) void k_apply2(const int* __restrict__ cnt,
                                                const int* __restrict__ bsum,
                                                int* __restrict__ row,
                                                int* __restrict__ cur,
                                                int N, int NB) {
  __shared__ int sboff;
  __shared__ int wsum[4];
  int b = blockIdx.x, t = threadIdx.x;
  if (t < 64) {
    int v = (t < NB) ? bsum[t] : 0;
    int incl = v;
    #pragma unroll
    for (int off = 1; off < 64; off <<= 1) {
      int tv = __shfl_up(incl, off);
      if (t >= off) incl += tv;
    }
    if (t == b) sboff = incl - v;                 // exclusive prefix at b
    if (b == 0 && t == NB - 1) row[N] = incl;     // grand total, written once
  }
  __syncthreads();

  int base = b * 1024 + t * 4;
  int4 c = {0, 0, 0, 0};
  if (base + 3 < N) c = *(const int4*)(cnt + base);
  else {
    if (base < N) c.x = cnt[base];
    if (base + 1 < N) c.y = cnt[base + 1];
    if (base + 2 < N) c.z = cnt[base + 2];
    if (base + 3 < N) c.w = cnt[base + 3];
  }
  int s = c.x + c.y + c.z + c.w;
  int incl = s;
  #pragma unroll
  for (int off = 1; off < 64; off <<= 1) {
    int tv = __shfl_up(incl, off);
    if ((t & 63) >= off) incl += tv;
  }
  int wid = t >> 6;
  if ((t & 63) == 63) wsum[wid] = incl;
  __syncthreads();
  int woff = 0;
  for (int w = 0; w < wid; ++w) woff += wsum[w];
  int ex = sboff + woff + incl - s;
  int r0 = ex, r1 = ex + c.x, r2 = r1 + c.y, r3 = r2 + c.z;
  if (base + 3 < N) {
    *(int4*)(row + base) = make_int4(r0, r1, r2, r3);
    *(int4*)(cur + base) = make_int4(r0, r1, r2, r3);
  } else {
    if (base < N)     { row[base] = r0;     cur[base] = r0; }
    if (base + 1 < N) { row[base + 1] = r1; cur[base + 1] = r1; }
    if (base + 2 < N) { row[base + 2] = r2; cur[base + 2] = r2; }
  }
}

// generic fallback scan kernels (NB > 64)
__global__ void k_bscan(const int* __restrict__ bsum, int* __restrict__ boff,
                        int* __restrict__ rowN, int NB) {
  int lane = threadIdx.x;
  int carry = 0;
  for (int base = 0; base < NB; base += 64) {
    int idx = base + lane;
    int v = (idx < NB) ? bsum[idx] : 0;
    int incl = v;
    #pragma unroll
    for (int off = 1; off < 64; off <<= 1) {
      int t = __shfl_up(incl, off);
      if (lane >= off) incl += t;
    }
    if (idx < NB) boff[idx] = carry + incl - v;
    carry += __shfl(incl, 63);
  }
  if (lane == 0) rowN[0] = carry;
}

__global__ __launch_bounds__(256) void k_apply(const int* __restrict__ cnt,
                                               const int* __restrict__ boff,
                                               int* __restrict__ row,
                                               int* __restrict__ cur, int N) {
  __shared__ int wsum[4];
  int b = blockIdx.x, t = threadIdx.x;
  int base = b * 1024 + t * 4;
  int4 c = {0, 0, 0, 0};
  if (base + 3 < N) c = *(const int4*)(cnt + base);
  else {
    if (base < N) c.x = cnt[base];
    if (base + 1 < N) c.y = cnt[base + 1];
    if (base + 2 < N) c.z = cnt[base + 2];
    if (base + 3 < N) c.w = cnt[base + 3];
  }
  int s = c.x + c.y + c.z + c.w;
  int incl = s;
  #pragma unroll
  for (int off = 1; off < 64; off <<= 1) {
    int tv = __shfl_up(incl, off);
    if ((t & 63) >= off) incl += tv;
  }
  int wid = t >> 6;
  if ((t & 63) == 63) wsum[wid] = incl;
  __syncthreads();
  int woff = 0;
  for (int w = 0; w < wid; ++w) woff += wsum[w];
  int ex = boff[b] + woff + incl - s;
  int r0 = ex, r1 = ex + c.x, r2 = r1 + c.y, r3 = r2 + c.z;
  if (base + 3 < N) {
    *(int4*)(row + base) = make_int4(r0, r1, r2, r3);
    *(int4*)(cur + base) = make_int4(r0, r1, r2, r3);
  } else {
    if (base < N)     { row[base] = r0;     cur[base] = r0; }
    if (base + 1 < N) { row[base + 1] = r1; cur[base + 1] = r1; }
    if (base + 2 < N) { row[base + 2] = r2; cur[base + 2] = r2; }
  }
}

__global__ __launch_bounds__(256) void k_fill(const int* __restrict__ src,
                                              const int* __restrict__ dst,
                                              int* __restrict__ cur,
                                              int* __restrict__ csr, int E) {
  int i = (blockIdx.x * blockDim.x + threadIdx.x) * 4;
  if (i + 3 < E) {
    int4 d = *(const int4*)(dst + i);
    int4 s = *(const int4*)(src + i);
    csr[atomicAdd(&cur[d.x], 1)] = s.x;
    csr[atomicAdd(&cur[d.y], 1)] = s.y;
    csr[atomicAdd(&cur[d.z], 1)] = s.z;
    csr[atomicAdd(&cur[d.w], 1)] = s.w;
  } else {
    for (int j = i; j < E; ++j) csr[atomicAdd(&cur[dst[j]], 1)] = src[j];
  }
}

// ---------------- h0 = l2_normalize(x), optional bf16 mirror ----------------
template<int USEB>
__global__ __launch_bounds__(256) void k_norm0(const float* __restrict__ x,
                                               float* __restrict__ h,
                                               uint2* __restrict__ hb, int N) {
  int gid = blockIdx.x * blockDim.x + threadIdx.x;
  int node = gid >> 5, lane = gid & 31;
  if (node >= N) return;
  float4 v = ((const float4*)x)[node * 32 + lane];
  float ss = v.x * v.x + v.y * v.y + v.z * v.z + v.w * v.w;
  #pragma unroll
  for (int off = 16; off; off >>= 1) ss += __shfl_xor(ss, off);
  float inv = 1.0f / fmaxf(sqrtf(ss), 1e-12f);
  float4 o; o.x = v.x * inv; o.y = v.y * inv; o.z = v.z * inv; o.w = v.w * inv;
  ((float4*)h)[node * 32 + lane] = o;
  if (USEB) {
    uint2 u;
    u.x = bf16r(o.x) | (bf16r(o.y) << 16);
    u.y = bf16r(o.z) | (bf16r(o.w) << 16);
    hb[node * 32 + lane] = u;
  }
}

// ---------------- one hop: fused alpha + aggregate + noise + normalize -------
// One wave per node. 4 groups of 16 lanes; each group handles 4 edges per
// iteration (16 edges/iter). Row = 16 lanes x 16B (8 bf16, packed).
// Noise (2 threefry/lane) hoisted BEFORE the gather loop so its ~110 VALU
// instrs can overlap gather latency; unpack+FMA interleaved per edge to cut
// peak VGPR pressure (~24 regs) for higher occupancy.
template<int USEB>
__global__ __launch_bounds__(256) void k_hop(
    const float* __restrict__ hpf, const uint4* __restrict__ hpb,
    float* __restrict__ hof, uint* __restrict__ hob, int wb,
    const int* __restrict__ row, const int* __restrict__ csr,
    int N, uint32_t k0, uint32_t k1) {
  int gid = blockIdx.x * blockDim.x + threadIdx.x;
  int node = gid >> 6;
  if (node >= N) return;
  int lane = threadIdx.x & 63;
  int sl = lane & 15, g = lane >> 4;

  int b = __builtin_amdgcn_readfirstlane(row[node]);
  int e = __builtin_amdgcn_readfirstlane(row[node + 1]);

  // noise first: independent of all gathers, overlaps csr/gather latency
  uint32_t j0 = (uint32_t)node * 128u + (uint32_t)sl * 8u + (uint32_t)g * 2u;
  float n0 = jax_normal(k0, k1, j0);
  float n1 = jax_normal(k0, k1, j0 + 1u);

#if HAVE_DOT2
  if (USEB) {
    uint4 hvp = hpb[node * 16 + sl];
    v2f acc[4] = {v2f{0.f,0.f}, v2f{0.f,0.f}, v2f{0.f,0.f}, v2f{0.f,0.f}};
    for (int cb = b; cb < e; cb += 64) {
      int cn = min(64, e - cb);
      int eidx = csr[min(cb + lane, e - 1)];
      for (int jb = 0; jb < cn; jb += 16) {
        int pos = jb + (g << 2);
        int i0 = __shfl(eidx, pos);
        int i1 = __shfl(eidx, pos + 1);
        int i2 = __shfl(eidx, pos + 2);
        int i3 = __shfl(eidx, pos + 3);
        uint4 u0 = hpb[i0 * 16 + sl];
        uint4 u1 = hpb[i1 * 16 + sl];
        uint4 u2 = hpb[i2 * 16 + sl];
        uint4 u3 = hpb[i3 * 16 + sl];
        float p0 = dot2b(u0.w, hvp.w, dot2b(u0.z, hvp.z, dot2b(u0.y, hvp.y, dot2b(u0.x, hvp.x, 0.f))));
        float p1 = dot2b(u1.w, hvp.w, dot2b(u1.z, hvp.z, dot2b(u1.y, hvp.y, dot2b(u1.x, hvp.x, 0.f))));
        float p2 = dot2b(u2.w, hvp.w, dot2b(u2.z, hvp.z, dot2b(u2.y, hvp.y, dot2b(u2.x, hvp.x, 0.f))));
        float p3 = dot2b(u3.w, hvp.w, dot2b(u3.z, hvp.z, dot2b(u3.y, hvp.y, dot2b(u3.x, hvp.x, 0.f))));
        #pragma unroll
        for (int off = 1; off < 16; off <<= 1) {
          p0 += __shfl_xor(p0, off);
          p1 += __shfl_xor(p1, off);
          p2 += __shfl_xor(p2, off);
          p3 += __shfl_xor(p3, off);
        }
        float al0 = (pos     < cn) ? __builtin_amdgcn_rcpf(1.0f + __expf(-p0)) : 0.f;
        float al1 = (pos + 1 < cn) ? __builtin_amdgcn_rcpf(1.0f + __expf(-p1)) : 0.f;
        float al2 = (pos + 2 < cn) ? __builtin_amdgcn_rcpf(1.0f + __expf(-p2)) : 0.f;
        float al3 = (pos + 3 < cn) ? __builtin_amdgcn_rcpf(1.0f + __expf(-p3)) : 0.f;
        // interleaved unpack + FMA (per edge) to cap register pressure
        {
          v2f a[4]; v2f vv = v2f{al0, al0};
          unpk8v(u0, a);
          #pragma unroll
          for (int t = 0; t < 4; ++t)
            acc[t] = __builtin_elementwise_fma(vv, a[t], acc[t]);
        }
        {
          v2f a[4]; v2f vv = v2f{al1, al1};
          unpk8v(u1, a);
          #pragma unroll
          for (int t = 0; t < 4; ++t)
            acc[t] = __builtin_elementwise_fma(vv, a[t], acc[t]);
        }
        {
          v2f a[4]; v2f vv = v2f{al2, al2};
          unpk8v(u2, a);
          #pragma unroll
          for (int t = 0; t < 4; ++t)
            acc[t] = __builtin_elementwise_fma(vv, a[t], acc[t]);
        }
        {
          v2f a[4]; v2f vv = v2f{al3, al3};
          unpk8v(u3, a);
          #pragma unroll
          for (int t = 0; t < 4; ++t)
            acc[t] = __builtin_elementwise_fma(vv, a[t], acc[t]);
        }
      }
    }
    // group combine on 8 scalars
    float ac[8] = {acc[0][0], acc[0][1], acc[1][0], acc[1][1],
                   acc[2][0], acc[2][1], acc[3][0], acc[3][1]};
    #pragma unroll
    for (int t = 0; t < 8; ++t) {
      ac[t] += __shfl_xor(ac[t], 16);
      ac[t] += __shfl_xor(ac[t], 32);
    }
    float p0s = (g & 1) ? ac[2] : ac[0];
    float p1s = (g & 1) ? ac[3] : ac[1];
    float q0s = (g & 1) ? ac[6] : ac[4];
    float q1s = (g & 1) ? ac[7] : ac[5];
    float s0 = (g & 2) ? q0s : p0s;
    float s1 = (g & 2) ? q1s : p1s;

    s0 += SIGMA * n0;
    s1 += SIGMA * n1;

    float ss = s0 * s0 + s1 * s1;
    #pragma unroll
    for (int off = 32; off; off >>= 1) ss += __shfl_xor(ss, off);
    float inv = __builtin_amdgcn_rcpf(fmaxf(sqrtf(ss), 1e-12f));
    float o0 = s0 * inv, o1 = s1 * inv;
    int oi = node * 64 + sl * 4 + g;
    ((float2*)hof)[oi] = make_float2(o0, o1);
    if (wb) hob[oi] = bf16r(o0) | (bf16r(o1) << 16);
    return;
  }
#endif

  // fallback / f32 path
  float hv[8];
  ldrow16<USEB>(hpf, hpb, node, sl, hv);
  float acc[8] = {0.f, 0.f, 0.f, 0.f, 0.f, 0.f, 0.f, 0.f};
  for (int cb = b; cb < e; cb += 64) {
    int cn = min(64, e - cb);
    int eidx = csr[min(cb + lane, e - 1)];
    for (int jb = 0; jb < cn; jb += 16) {
      int pos = jb + (g << 2);
      int i0 = __shfl(eidx, pos);
      int i1 = __shfl(eidx, pos + 1);
      int i2 = __shfl(eidx, pos + 2);
      int i3 = __shfl(eidx, pos + 3);
      float a0[8], a1[8], a2[8], a3[8];
      ldrow16<USEB>(hpf, hpb, i0, sl, a0);
      ldrow16<USEB>(hpf, hpb, i1, sl, a1);
      ldrow16<USEB>(hpf, hpb, i2, sl, a2);
      ldrow16<USEB>(hpf, hpb, i3, sl, a3);
      float p0 = 0.f, p1 = 0.f, p2 = 0.f, p3 = 0.f;
      #pragma unroll
      for (int t = 0; t < 8; ++t) {
        p0 = fmaf(a0[t], hv[t], p0);
        p1 = fmaf(a1[t], hv[t], p1);
        p2 = fmaf(a2[t], hv[t], p2);
        p3 = fmaf(a3[t], hv[t], p3);
      }
      #pragma unroll
      for (int off = 1; off < 16; off <<= 1) {
        p0 += __shfl_xor(p0, off);
        p1 += __shfl_xor(p1, off);
        p2 += __shfl_xor(p2, off);
        p3 += __shfl_xor(p3, off);
      }
      float al0 = (pos     < cn) ? __builtin_amdgcn_rcpf(1.0f + __expf(-p0)) : 0.f;
      float al1 = (pos + 1 < cn) ? __builtin_amdgcn_rcpf(1.0f + __expf(-p1)) : 0.f;
      float al2 = (pos + 2 < cn) ? __builtin_amdgcn_rcpf(1.0f + __expf(-p2)) : 0.f;
      float al3 = (pos + 3 < cn) ? __builtin_amdgcn_rcpf(1.0f + __expf(-p3)) : 0.f;
      #pragma unroll
      for (int t = 0; t < 8; ++t) {
        acc[t] = fmaf(al0, a0[t], acc[t]);
        acc[t] = fmaf(al1, a1[t], acc[t]);
        acc[t] = fmaf(al2, a2[t], acc[t]);
        acc[t] = fmaf(al3, a3[t], acc[t]);
      }
    }
  }
  #pragma unroll
  for (int t = 0; t < 8; ++t) {
    acc[t] += __shfl_xor(acc[t], 16);
    acc[t] += __shfl_xor(acc[t], 32);
  }
  float p0s = (g & 1) ? acc[2] : acc[0];
  float p1s = (g & 1) ? acc[3] : acc[1];
  float q0s = (g & 1) ? acc[6] : acc[4];
  float q1s = (g & 1) ? acc[7] : acc[5];
  float s0 = (g & 2) ? q0s : p0s;
  float s1 = (g & 2) ? q1s : p1s;

  s0 += SIGMA * n0;
  s1 += SIGMA * n1;

  float ss = s0 * s0 + s1 * s1;
  #pragma unroll
  for (int off = 32; off; off >>= 1) ss += __shfl_xor(ss, off);
  float inv = __builtin_amdgcn_rcpf(fmaxf(sqrtf(ss), 1e-12f));
  float o0 = s0 * inv, o1 = s1 * inv;
  int oi = node * 64 + sl * 4 + g;
  ((float2*)hof)[oi] = make_float2(o0, o1);
  if (USEB && wb) hob[oi] = bf16r(o0) | (bf16r(o1) << 16);
}

extern "C" void kernel_launch(void* const* d_in, const int* in_sizes, int n_in,
                              void* d_out, int out_size, void* d_ws, size_t ws_size,
                              hipStream_t stream) {
  const float* x = (const float*)d_in[0];
  const int* ei = (const int*)d_in[1];
  int N = in_sizes[0] / D;
  int E = in_sizes[1] / 2;
  const int* src = ei;
  const int* dst = ei + E;
  float* out = (float*)d_out;
  size_t nd = (size_t)N * D;

  int Np = (N + 3) & ~3;
  int Ep = (E + 3) & ~3;
  int NB = (N + 1023) / 1024;
  int NBp = (NB + 3) & ~3;
  int* cnt  = (int*)d_ws;             // Np
  int* row  = cnt + Np;               // Np + 4
  int* cur  = row + Np + 4;           // Np
  int* csr  = cur + Np;               // Ep
  int* bsum = csr + Ep;               // NBp
  int* boff = bsum + NBp;             // NBp

  size_t int_bytes = ((size_t)(3 * Np + 4 + Ep + 2 * NBp)) * 4;
  size_t hb_off = (int_bytes + 255) & ~(size_t)255;
  size_t hb_bytes = (size_t)N * D * 2;      // one bf16 h buffer
  bool useb = ws_size >= hb_off + 2 * hb_bytes;
  ushort* hb0 = (ushort*)((char*)d_ws + hb_off);
  ushort* hb1 = hb0 + (size_t)N * D;

  int n4 = Np / 4;
  k_zero<<<(n4 + 255) / 256, 256, 0, stream>>>((int4*)cnt, n4);
  int eb4 = (E / 4 + 256) / 256;
  k_hist<<<eb4, 256, 0, stream>>>(dst, cnt, E);
  k_bsum<<<NB, 256, 0, stream>>>(cnt, bsum, N);
  if (NB <= 64) {
    k_apply2<<<NB, 256, 0, stream>>>(cnt, bsum, row, cur, N, NB);
  } else {
    k_bscan<<<1, 64, 0, stream>>>(bsum, boff, row + N, NB);
    k_apply<<<NB, 256, 0, stream>>>(cnt, boff, row, cur, N);
  }
  k_fill<<<eb4, 256, 0, stream>>>(src, dst, cur, csr, E);

  int nb32 = (N * 32 + 255) / 256;
  int nb64 = (N * 64 + 255) / 256;

  if (useb) {
    k_norm0<1><<<nb32, 256, 0, stream>>>(x, out, (uint2*)hb0, N);
    for (int k = 0; k < 3; ++k) {
      uint32_t ka, kb;
      tf2x32(0u, 42u, 0u, (uint32_t)k, ka, kb);
      const uint4* hin = (const uint4*)((k & 1) ? hb1 : hb0);
      uint* hout = (uint*)((k & 1) ? hb0 : hb1);
      k_hop<1><<<nb64, 256, 0, stream>>>(nullptr, hin,
                                         out + (size_t)(k + 1) * nd, hout,
                                         (k < 2) ? 1 : 0,
                                         row, csr, N, ka, kb);
    }
  } else {
    k_norm0<0><<<nb32, 256, 0, stream>>>(x, out, nullptr, N);
    for (int k = 0; k < 3; ++k) {
      uint32_t ka, kb;
      tf2x32(0u, 42u, 0u, (uint32_t)k, ka, kb);
      k_hop<0><<<nb64, 256, 0, stream>>>(out + (size_t)k * nd, nullptr,
                                         out + (size_t)(k + 1) * nd, nullptr, 0,
                                         row, csr, N, ka, kb);
    }
  }
}

// Round 9
// 169.714 us; speedup vs baseline: 1.2200x; 1.0699x over previous
//
#include <hip/hip_runtime.h>
#include <stdint.h>

#define D 128
#define SIGMA 0.1f

typedef unsigned int uint;
typedef unsigned short ushort;

#if __has_builtin(__builtin_amdgcn_fdot2_f32_bf16)
#define HAVE_DOT2 1
typedef __bf16 bf16x2 __attribute__((ext_vector_type(2)));
__device__ inline float dot2b(uint a, uint b, float c) {
  union { uint u; bf16x2 v; } ua, ub;
  ua.u = a; ub.u = b;
  return __builtin_amdgcn_fdot2_f32_bf16(ua.v, ub.v, c, false);
}
#else
#define HAVE_DOT2 0
#endif

typedef float v2f __attribute__((ext_vector_type(2)));

// ---------------- Threefry-2x32 (20 rounds), matches JAX/XLA ----------------
__host__ __device__ inline void tf2x32(uint32_t k0, uint32_t k1,
                                       uint32_t x0, uint32_t x1,
                                       uint32_t& o0, uint32_t& o1) {
  const uint32_t ks2 = k0 ^ k1 ^ 0x1BD11BDAu;
#define ROTL(v, r) (((v) << (r)) | ((v) >> (32 - (r))))
#define RND(R) { x0 += x1; x1 = ROTL(x1, R); x1 ^= x0; }
  x0 += k0; x1 += k1;
  RND(13) RND(15) RND(26) RND(6)
  x0 += k1; x1 += ks2 + 1u;
  RND(17) RND(29) RND(16) RND(24)
  x0 += ks2; x1 += k0 + 2u;
  RND(13) RND(15) RND(26) RND(6)
  x0 += k0; x1 += k1 + 3u;
  RND(17) RND(29) RND(16) RND(24)
  x0 += k1; x1 += ks2 + 4u;
  RND(13) RND(15) RND(26) RND(6)
  x0 += ks2; x1 += k0 + 5u;
#undef RND
#undef ROTL
  o0 = x0; o1 = x1;
}

// JAX partitionable random_bits (32-bit): bits[j] = o0 ^ o1 of block(key,(0,j)),
// then uniform in [-1+ulp, 1), then erfinv poly (XLA Giles f32). Returns p*u;
// caller multiplies by sqrt(2)*SIGMA folded into one constant.
__device__ inline float jax_normal_pu(uint32_t k0, uint32_t k1, uint32_t idx) {
  uint32_t o0, o1;
  tf2x32(k0, k1, 0u, idx, o0, o1);
  uint32_t bits = o0 ^ o1;
  float f = __uint_as_float((bits >> 9) | 0x3f800000u) - 1.0f;
  const float lo = __uint_as_float(0xBF7FFFFFu); // nextafter(-1,0)
  float u = fmaxf(lo, f * 2.0f + lo);
  float w = -__logf((1.0f - u) * (1.0f + u));    // = -log1p(-u*u)
  float p;
  if (w < 5.0f) {
    w -= 2.5f;
    p = 2.81022636e-08f;
    p = fmaf(p, w, 3.43273939e-07f);
    p = fmaf(p, w, -3.5233877e-06f);
    p = fmaf(p, w, -4.39150654e-06f);
    p = fmaf(p, w, 0.00021858087f);
    p = fmaf(p, w, -0.00125372503f);
    p = fmaf(p, w, -0.00417768164f);
    p = fmaf(p, w, 0.246640727f);
    p = fmaf(p, w, 1.50140941f);
  } else {
    w = sqrtf(w) - 3.0f;
    p = -0.000200214257f;
    p = fmaf(p, w, 0.000100950558f);
    p = fmaf(p, w, 0.00134934322f);
    p = fmaf(p, w, -0.00367342844f);
    p = fmaf(p, w, 0.00573950773f);
    p = fmaf(p, w, -0.0076224613f);
    p = fmaf(p, w, 0.00943887047f);
    p = fmaf(p, w, 1.00167406f);
    p = fmaf(p, w, 2.83297682f);
  }
  return p * u;
}
#define NOISE_SCALE 0.14142135624f   // sqrt(2) * SIGMA

__device__ inline uint bf16r(float f) {  // round-to-nearest-even bf16 bits
  uint u = __float_as_uint(f);
  return (u + 0x7fffu + ((u >> 16) & 1u)) >> 16;
}

// unpack 8 bf16 (uint4) -> 8 floats
__device__ inline void unpk8(uint4 u, float* a) {
  a[0] = __uint_as_float(u.x << 16);
  a[1] = __uint_as_float(u.x & 0xffff0000u);
  a[2] = __uint_as_float(u.y << 16);
  a[3] = __uint_as_float(u.y & 0xffff0000u);
  a[4] = __uint_as_float(u.z << 16);
  a[5] = __uint_as_float(u.z & 0xffff0000u);
  a[6] = __uint_as_float(u.w << 16);
  a[7] = __uint_as_float(u.w & 0xffff0000u);
}

// unpack 8 bf16 (uint4) -> 4x v2f
__device__ inline void unpk8v(uint4 u, v2f* a) {
  a[0] = v2f{__uint_as_float(u.x << 16), __uint_as_float(u.x & 0xffff0000u)};
  a[1] = v2f{__uint_as_float(u.y << 16), __uint_as_float(u.y & 0xffff0000u)};
  a[2] = v2f{__uint_as_float(u.z << 16), __uint_as_float(u.z & 0xffff0000u)};
  a[3] = v2f{__uint_as_float(u.w << 16), __uint_as_float(u.w & 0xffff0000u)};
}

template<int USEB>
__device__ inline void ldrow16(const float* __restrict__ hf,
                               const uint4* __restrict__ hb,
                               int node, int sl, float* a) {
  if (USEB) {
    unpk8(hb[node * 16 + sl], a);
  } else {
    float4 v0 = ((const float4*)hf)[node * 32 + sl * 2];
    float4 v1 = ((const float4*)hf)[node * 32 + sl * 2 + 1];
    a[0] = v0.x; a[1] = v0.y; a[2] = v0.z; a[3] = v0.w;
    a[4] = v1.x; a[5] = v1.y; a[6] = v1.z; a[7] = v1.w;
  }
}

// ---------------- workspace zeroing (rocclr fillBuffer has huge latency) ----
__global__ __launch_bounds__(256) void k_zero(int4* __restrict__ p, int n4) {
  int i = blockIdx.x * blockDim.x + threadIdx.x;
  if (i < n4) p[i] = make_int4(0, 0, 0, 0);
}

// ---------------- CSR build ----------------
__global__ __launch_bounds__(256) void k_hist(const int* __restrict__ dst,
                                              int* __restrict__ cnt, int E) {
  int i = (blockIdx.x * blockDim.x + threadIdx.x) * 4;
  if (i + 3 < E) {
    int4 d = *(const int4*)(dst + i);
    atomicAdd(&cnt[d.x], 1);
    atomicAdd(&cnt[d.y], 1);
    atomicAdd(&cnt[d.z], 1);
    atomicAdd(&cnt[d.w], 1);
  } else {
    for (int j = i; j < E; ++j) atomicAdd(&cnt[dst[j]], 1);
  }
}

__global__ __launch_bounds__(256) void k_bsum(const int* __restrict__ cnt,
                                              int* __restrict__ bsum, int N) {
  __shared__ int ws[4];
  int b = blockIdx.x, t = threadIdx.x;
  int base = b * 1024 + t * 4;
  int4 c = {0, 0, 0, 0};
  if (base + 3 < N) c = *(const int4*)(cnt + base);
  else {
    if (base < N) c.x = cnt[base];
    if (base + 1 < N) c.y = cnt[base + 1];
    if (base + 2 < N) c.z = cnt[base + 2];
    if (base + 3 < N) c.w = cnt[base + 3];
  }
  int s = c.x + c.y + c.z + c.w;
  #pragma unroll
  for (int off = 32; off; off >>= 1) s += __shfl_xor(s, off);
  if ((t & 63) == 0) ws[t >> 6] = s;
  __syncthreads();
  if (t == 0) bsum[b] = ws[0] + ws[1] + ws[2] + ws[3];
}

// apply with fused block-sum scan (NB <= 64): no separate k_bscan dispatch
__global__ __launch_bounds__(256) void k_apply2(const int* __restrict__ cnt,
                                                const int* __restrict__ bsum,
                                                int* __restrict__ row,
                                                int* __restrict__ cur,
                                                int N, int NB) {
  __shared__ int sboff;
  __shared__ int wsum[4];
  int b = blockIdx.x, t = threadIdx.x;
  if (t < 64) {
    int v = (t < NB) ? bsum[t] : 0;
    int incl = v;
    #pragma unroll
    for (int off = 1; off < 64; off <<= 1) {
      int tv = __shfl_up(incl, off);
      if (t >= off) incl += tv;
    }
    if (t == b) sboff = incl - v;                 // exclusive prefix at b
    if (b == 0 && t == NB - 1) row[N] = incl;     // grand total, written once
  }
  __syncthreads();

  int base = b * 1024 + t * 4;
  int4 c = {0, 0, 0, 0};
  if (base + 3 < N) c = *(const int4*)(cnt + base);
  else {
    if (base < N) c.x = cnt[base];
    if (base + 1 < N) c.y = cnt[base + 1];
    if (base + 2 < N) c.z = cnt[base + 2];
    if (base + 3 < N) c.w = cnt[base + 3];
  }
  int s = c.x + c.y + c.z + c.w;
  int incl = s;
  #pragma unroll
  for (int off = 1; off < 64; off <<= 1) {
    int tv = __shfl_up(incl, off);
    if ((t & 63) >= off) incl += tv;
  }
  int wid = t >> 6;
  if ((t & 63) == 63) wsum[wid] = incl;
  __syncthreads();
  int woff = 0;
  for (int w = 0; w < wid; ++w) woff += wsum[w];
  int ex = sboff + woff + incl - s;
  int r0 = ex, r1 = ex + c.x, r2 = r1 + c.y, r3 = r2 + c.z;
  if (base + 3 < N) {
    *(int4*)(row + base) = make_int4(r0, r1, r2, r3);
    *(int4*)(cur + base) = make_int4(r0, r1, r2, r3);
  } else {
    if (base < N)     { row[base] = r0;     cur[base] = r0; }
    if (base + 1 < N) { row[base + 1] = r1; cur[base + 1] = r1; }
    if (base + 2 < N) { row[base + 2] = r2; cur[base + 2] = r2; }
  }
}

// generic fallback scan kernels (NB > 64)
__global__ void k_bscan(const int* __restrict__ bsum, int* __restrict__ boff,
                        int* __restrict__ rowN, int NB) {
  int lane = threadIdx.x;
  int carry = 0;
  for (int base = 0; base < NB; base += 64) {
    int idx = base + lane;
    int v = (idx < NB) ? bsum[idx] : 0;
    int incl = v;
    #pragma unroll
    for (int off = 1; off < 64; off <<= 1) {
      int t = __shfl_up(incl, off);
      if (lane >= off) incl += t;
    }
    if (idx < NB) boff[idx] = carry + incl - v;
    carry += __shfl(incl, 63);
  }
  if (lane == 0) rowN[0] = carry;
}

__global__ __launch_bounds__(256) void k_apply(const int* __restrict__ cnt,
                                               const int* __restrict__ boff,
                                               int* __restrict__ row,
                                               int* __restrict__ cur, int N) {
  __shared__ int wsum[4];
  int b = blockIdx.x, t = threadIdx.x;
  int base = b * 1024 + t * 4;
  int4 c = {0, 0, 0, 0};
  if (base + 3 < N) c = *(const int4*)(cnt + base);
  else {
    if (base < N) c.x = cnt[base];
    if (base + 1 < N) c.y = cnt[base + 1];
    if (base + 2 < N) c.z = cnt[base + 2];
    if (base + 3 < N) c.w = cnt[base + 3];
  }
  int s = c.x + c.y + c.z + c.w;
  int incl = s;
  #pragma unroll
  for (int off = 1; off < 64; off <<= 1) {
    int tv = __shfl_up(incl, off);
    if ((t & 63) >= off) incl += tv;
  }
  int wid = t >> 6;
  if ((t & 63) == 63) wsum[wid] = incl;
  __syncthreads();
  int woff = 0;
  for (int w = 0; w < wid; ++w) woff += wsum[w];
  int ex = boff[b] + woff + incl - s;
  int r0 = ex, r1 = ex + c.x, r2 = r1 + c.y, r3 = r2 + c.z;
  if (base + 3 < N) {
    *(int4*)(row + base) = make_int4(r0, r1, r2, r3);
    *(int4*)(cur + base) = make_int4(r0, r1, r2, r3);
  } else {
    if (base < N)     { row[base] = r0;     cur[base] = r0; }
    if (base + 1 < N) { row[base + 1] = r1; cur[base + 1] = r1; }
    if (base + 2 < N) { row[base + 2] = r2; cur[base + 2] = r2; }
  }
}

__global__ __launch_bounds__(256) void k_fill(const int* __restrict__ src,
                                              const int* __restrict__ dst,
                                              int* __restrict__ cur,
                                              int* __restrict__ csr, int E) {
  int i = (blockIdx.x * blockDim.x + threadIdx.x) * 4;
  if (i + 3 < E) {
    int4 d = *(const int4*)(dst + i);
    int4 s = *(const int4*)(src + i);
    csr[atomicAdd(&cur[d.x], 1)] = s.x;
    csr[atomicAdd(&cur[d.y], 1)] = s.y;
    csr[atomicAdd(&cur[d.z], 1)] = s.z;
    csr[atomicAdd(&cur[d.w], 1)] = s.w;
  } else {
    for (int j = i; j < E; ++j) csr[atomicAdd(&cur[dst[j]], 1)] = src[j];
  }
}

// ---------------- h0 = l2_normalize(x), optional bf16 mirror ----------------
template<int USEB>
__global__ __launch_bounds__(256) void k_norm0(const float* __restrict__ x,
                                               float* __restrict__ h,
                                               uint2* __restrict__ hb, int N) {
  int gid = blockIdx.x * blockDim.x + threadIdx.x;
  int node = gid >> 5, lane = gid & 31;
  if (node >= N) return;
  float4 v = ((const float4*)x)[node * 32 + lane];
  float ss = v.x * v.x + v.y * v.y + v.z * v.z + v.w * v.w;
  #pragma unroll
  for (int off = 16; off; off >>= 1) ss += __shfl_xor(ss, off);
  float inv = 1.0f / fmaxf(sqrtf(ss), 1e-12f);
  float4 o; o.x = v.x * inv; o.y = v.y * inv; o.z = v.z * inv; o.w = v.w * inv;
  ((float4*)h)[node * 32 + lane] = o;
  if (USEB) {
    uint2 u;
    u.x = bf16r(o.x) | (bf16r(o.y) << 16);
    u.y = bf16r(o.z) | (bf16r(o.w) << 16);
    hb[node * 32 + lane] = u;
  }
}

// ---------------- one hop: fused alpha + aggregate + noise + normalize -------
// One wave per node, 4 groups of 16 lanes, row = 16 lanes x 16B (8 bf16).
// Slot mapping slot = j*4 + g: gather u_j covers slots [4j,4j+4), so only
// ceil(rem/4) gather+process blocks are issued (wave-uniform branches) —
// cuts the ~6 dead slots/node of the fixed-16 quantum at avg degree 10.
template<int USEB>
__global__ __launch_bounds__(256) void k_hop(
    const float* __restrict__ hpf, const uint4* __restrict__ hpb,
    float* __restrict__ hof, uint* __restrict__ hob, int wb,
    const int* __restrict__ row, const int* __restrict__ csr,
    int N, uint32_t k0, uint32_t k1) {
  int gid = blockIdx.x * blockDim.x + threadIdx.x;
  int node = gid >> 6;
  if (node >= N) return;
  int lane = threadIdx.x & 63;
  int sl = lane & 15, g = lane >> 4;

  int b = __builtin_amdgcn_readfirstlane(row[node]);
  int e = __builtin_amdgcn_readfirstlane(row[node + 1]);

  // noise first: independent of all gathers, overlaps csr/gather latency
  uint32_t j0 = (uint32_t)node * 128u + (uint32_t)sl * 8u + (uint32_t)g * 2u;
  float n0 = jax_normal_pu(k0, k1, j0);
  float n1 = jax_normal_pu(k0, k1, j0 + 1u);

#if HAVE_DOT2
  if (USEB) {
    uint4 hvp = hpb[node * 16 + sl];
    v2f acc[4] = {v2f{0.f,0.f}, v2f{0.f,0.f}, v2f{0.f,0.f}, v2f{0.f,0.f}};

    for (int cb = b; cb < e; cb += 64) {
      int cn = min(64, e - cb);
      int eidx = csr[min(cb + lane, e - 1)];
      for (int jb = 0; jb < cn; jb += 16) {
        int rem = cn - jb;   // wave-uniform, >= 1
        // ---- load cascade (keeps up to ceil(rem/4) gathers in flight) ----
        uint4 u0, u1, u2, u3;
        {
          int i0 = __shfl(eidx, jb + g);
          u0 = hpb[i0 * 16 + sl];
        }
        if (rem > 4)  { int i1 = __shfl(eidx, jb + 4 + g);  u1 = hpb[i1 * 16 + sl]; }
        if (rem > 8)  { int i2 = __shfl(eidx, jb + 8 + g);  u2 = hpb[i2 * 16 + sl]; }
        if (rem > 12) { int i3 = __shfl(eidx, jb + 12 + g); u3 = hpb[i3 * 16 + sl]; }

        // ---- process cascade ----
        #define PROC(UU, SBASE)                                                 \
        {                                                                       \
          float p = dot2b(UU.w, hvp.w, dot2b(UU.z, hvp.z,                       \
                    dot2b(UU.y, hvp.y, dot2b(UU.x, hvp.x, 0.f))));              \
          p += __shfl_xor(p, 1);                                                \
          p += __shfl_xor(p, 2);                                                \
          p += __shfl_xor(p, 4);                                                \
          p += __shfl_xor(p, 8);                                                \
          float al = ((SBASE) + g < rem)                                        \
                       ? __builtin_amdgcn_rcpf(1.0f + __expf(-p)) : 0.f;        \
          v2f a[4]; v2f vv = v2f{al, al};                                       \
          unpk8v(UU, a);                                                        \
          acc[0] = __builtin_elementwise_fma(vv, a[0], acc[0]);                 \
          acc[1] = __builtin_elementwise_fma(vv, a[1], acc[1]);                 \
          acc[2] = __builtin_elementwise_fma(vv, a[2], acc[2]);                 \
          acc[3] = __builtin_elementwise_fma(vv, a[3], acc[3]);                 \
        }
        PROC(u0, 0)
        if (rem > 4)  PROC(u1, 4)
        if (rem > 8)  PROC(u2, 8)
        if (rem > 12) PROC(u3, 12)
        #undef PROC
      }
    }

    // group combine on 8 scalars
    float ac[8] = {acc[0][0], acc[0][1], acc[1][0], acc[1][1],
                   acc[2][0], acc[2][1], acc[3][0], acc[3][1]};
    #pragma unroll
    for (int t = 0; t < 8; ++t) {
      ac[t] += __shfl_xor(ac[t], 16);
      ac[t] += __shfl_xor(ac[t], 32);
    }
    float p0s = (g & 1) ? ac[2] : ac[0];
    float p1s = (g & 1) ? ac[3] : ac[1];
    float q0s = (g & 1) ? ac[6] : ac[4];
    float q1s = (g & 1) ? ac[7] : ac[5];
    float s0 = (g & 2) ? q0s : p0s;
    float s1 = (g & 2) ? q1s : p1s;

    s0 += NOISE_SCALE * n0;
    s1 += NOISE_SCALE * n1;

    float ss = s0 * s0 + s1 * s1;
    #pragma unroll
    for (int off = 32; off; off >>= 1) ss += __shfl_xor(ss, off);
    float inv = __builtin_amdgcn_rcpf(fmaxf(sqrtf(ss), 1e-12f));
    float o0 = s0 * inv, o1 = s1 * inv;
    int oi = node * 64 + sl * 4 + g;
    ((float2*)hof)[oi] = make_float2(o0, o1);
    if (wb) hob[oi] = bf16r(o0) | (bf16r(o1) << 16);
    return;
  }
#endif

  // fallback / f32 path
  float hv[8];
  ldrow16<USEB>(hpf, hpb, node, sl, hv);
  float acc[8] = {0.f, 0.f, 0.f, 0.f, 0.f, 0.f, 0.f, 0.f};
  for (int cb = b; cb < e; cb += 64) {
    int cn = min(64, e - cb);
    int eidx = csr[min(cb + lane, e - 1)];
    for (int jb = 0; jb < cn; jb += 16) {
      int pos = jb + (g << 2);
      int i0 = __shfl(eidx, pos);
      int i1 = __shfl(eidx, pos + 1);
      int i2 = __shfl(eidx, pos + 2);
      int i3 = __shfl(eidx, pos + 3);
      float a0[8], a1[8], a2[8], a3[8];
      ldrow16<USEB>(hpf, hpb, i0, sl, a0);
      ldrow16<USEB>(hpf, hpb, i1, sl, a1);
      ldrow16<USEB>(hpf, hpb, i2, sl, a2);
      ldrow16<USEB>(hpf, hpb, i3, sl, a3);
      float p0 = 0.f, p1 = 0.f, p2 = 0.f, p3 = 0.f;
      #pragma unroll
      for (int t = 0; t < 8; ++t) {
        p0 = fmaf(a0[t], hv[t], p0);
        p1 = fmaf(a1[t], hv[t], p1);
        p2 = fmaf(a2[t], hv[t], p2);
        p3 = fmaf(a3[t], hv[t], p3);
      }
      #pragma unroll
      for (int off = 1; off < 16; off <<= 1) {
        p0 += __shfl_xor(p0, off);
        p1 += __shfl_xor(p1, off);
        p2 += __shfl_xor(p2, off);
        p3 += __shfl_xor(p3, off);
      }
      float al0 = (pos     < cn) ? __builtin_amdgcn_rcpf(1.0f + __expf(-p0)) : 0.f;
      float al1 = (pos + 1 < cn) ? __builtin_amdgcn_rcpf(1.0f + __expf(-p1)) : 0.f;
      float al2 = (pos + 2 < cn) ? __builtin_amdgcn_rcpf(1.0f + __expf(-p2)) : 0.f;
      float al3 = (pos + 3 < cn) ? __builtin_amdgcn_rcpf(1.0f + __expf(-p3)) : 0.f;
      #pragma unroll
      for (int t = 0; t < 8; ++t) {
        acc[t] = fmaf(al0, a0[t], acc[t]);
        acc[t] = fmaf(al1, a1[t], acc[t]);
        acc[t] = fmaf(al2, a2[t], acc[t]);
        acc[t] = fmaf(al3, a3[t], acc[t]);
      }
    }
  }
  #pragma unroll
  for (int t = 0; t < 8; ++t) {
    acc[t] += __shfl_xor(acc[t], 16);
    acc[t] += __shfl_xor(acc[t], 32);
  }
  float p0s = (g & 1) ? acc[2] : acc[0];
  float p1s = (g & 1) ? acc[3] : acc[1];
  float q0s = (g & 1) ? acc[6] : acc[4];
  float q1s = (g & 1) ? acc[7] : acc[5];
  float s0 = (g & 2) ? q0s : p0s;
  float s1 = (g & 2) ? q1s : p1s;

  s0 += NOISE_SCALE * n0;
  s1 += NOISE_SCALE * n1;

  float ss = s0 * s0 + s1 * s1;
  #pragma unroll
  for (int off = 32; off; off >>= 1) ss += __shfl_xor(ss, off);
  float inv = __builtin_amdgcn_rcpf(fmaxf(sqrtf(ss), 1e-12f));
  float o0 = s0 * inv, o1 = s1 * inv;
  int oi = node * 64 + sl * 4 + g;
  ((float2*)hof)[oi] = make_float2(o0, o1);
  if (USEB && wb) hob[oi] = bf16r(o0) | (bf16r(o1) << 16);
}

extern "C" void kernel_launch(void* const* d_in, const int* in_sizes, int n_in,
                              void* d_out, int out_size, void* d_ws, size_t ws_size,
                              hipStream_t stream) {
  const float* x = (const float*)d_in[0];
  const int* ei = (const int*)d_in[1];
  int N = in_sizes[0] / D;
  int E = in_sizes[1] / 2;
  const int* src = ei;
  const int* dst = ei + E;
  float* out = (float*)d_out;
  size_t nd = (size_t)N * D;

  int Np = (N + 3) & ~3;
  int Ep = (E + 3) & ~3;
  int NB = (N + 1023) / 1024;
  int NBp = (NB + 3) & ~3;
  int* cnt  = (int*)d_ws;             // Np
  int* row  = cnt + Np;               // Np + 4
  int* cur  = row + Np + 4;           // Np
  int* csr  = cur + Np;               // Ep
  int* bsum = csr + Ep;               // NBp
  int* boff = bsum + NBp;             // NBp

  size_t int_bytes = ((size_t)(3 * Np + 4 + Ep + 2 * NBp)) * 4;
  size_t hb_off = (int_bytes + 255) & ~(size_t)255;
  size_t hb_bytes = (size_t)N * D * 2;      // one bf16 h buffer
  bool useb = ws_size >= hb_off + 2 * hb_bytes;
  ushort* hb0 = (ushort*)((char*)d_ws + hb_off);
  ushort* hb1 = hb0 + (size_t)N * D;

  int n4 = Np / 4;
  k_zero<<<(n4 + 255) / 256, 256, 0, stream>>>((int4*)cnt, n4);
  int eb4 = (E / 4 + 256) / 256;
  k_hist<<<eb4, 256, 0, stream>>>(dst, cnt, E);
  k_bsum<<<NB, 256, 0, stream>>>(cnt, bsum, N);
  if (NB <= 64) {
    k_apply2<<<NB, 256, 0, stream>>>(cnt, bsum, row, cur, N, NB);
  } else {
    k_bscan<<<1, 64, 0, stream>>>(bsum, boff, row + N, NB);
    k_apply<<<NB, 256, 0, stream>>>(cnt, boff, row, cur, N);
  }
  k_fill<<<eb4, 256, 0, stream>>>(src, dst, cur, csr, E);

  int nb32 = (N * 32 + 255) / 256;
  int nb64 = (N * 64 + 255) / 256;

  if (useb) {
    k_norm0<1><<<nb32, 256, 0, stream>>>(x, out, (uint2*)hb0, N);
    for (int k = 0; k < 3; ++k) {
      uint32_t ka, kb;
      tf2x32(0u, 42u, 0u, (uint32_t)k, ka, kb);
      const uint4* hin = (const uint4*)((k & 1) ? hb1 : hb0);
      uint* hout = (uint*)((k & 1) ? hb0 : hb1);
      k_hop<1><<<nb64, 256, 0, stream>>>(nullptr, hin,
                                         out + (size_t)(k + 1) * nd, hout,
                                         (k < 2) ? 1 : 0,
                                         row, csr, N, ka, kb);
    }
  } else {
    k_norm0<0><<<nb32, 256, 0, stream>>>(x, out, nullptr, N);
    for (int k = 0; k < 3; ++k) {
      uint32_t ka, kb;
      tf2x32(0u, 42u, 0u, (uint32_t)k, ka, kb);
      k_hop<0><<<nb64, 256, 0, stream>>>(out + (size_t)k * nd, nullptr,
                                         out + (size_t)(k + 1) * nd, nullptr, 0,
                                         row, csr, N, ka, kb);
    }
  }
}